// Round 12
// baseline (888.928 us; speedup 1.0000x reference)
//
#include <hip/hip_runtime.h>
#include <math.h>

#define T_TOK 1024
#define H_DIM 2048
#define N_EXP 32
#define TOPK  4
#define F_DIM 768
#define FS_DIM 4096
#define FS_HALF 2048

typedef __bf16 bf16;
typedef __attribute__((ext_vector_type(2))) __bf16 bf16x2;
typedef __attribute__((ext_vector_type(4))) __bf16 bf16x4;
typedef __attribute__((ext_vector_type(8))) __bf16 bf16x8;
typedef __attribute__((ext_vector_type(4))) float f32x4;

// raw barrier: drain ds ops (lgkm) but let global prefetch loads stay in
// flight across the barrier; sched_barrier(0) pins code motion at the BAR.
#define BAR() do {                                        \
    asm volatile("s_waitcnt lgkmcnt(0)" ::: "memory");    \
    __builtin_amdgcn_s_barrier();                         \
    __builtin_amdgcn_sched_barrier(0);                    \
  } while (0)

// XOR-swizzled LDS offset: rows are 32 bf16 = 64B.
__device__ __forceinline__ int swz(int row, int colB) {
  return row * 64 + (colB ^ (((row >> 2) & 3) << 4));
}

// ---------------- router: fp32 logits -> softmax -> top4 -> lists ----------------
__global__ __launch_bounds__(256) void router_kernel(
    const float* __restrict__ x, const float* __restrict__ rw,
    const float* __restrict__ sgw,
    float* __restrict__ topw, float* __restrict__ sg,
    int* __restrict__ counts, int* __restrict__ lists)
{
  int t = blockIdx.x; int tid = threadIdx.x;
  int lane = tid & 63, wave = tid >> 6;
  float acc[N_EXP];
  #pragma unroll
  for (int e = 0; e < N_EXP; e++) acc[e] = 0.f;
  float accs = 0.f;
  const float* xr = x + (size_t)t * H_DIM;
  for (int h = tid; h < H_DIM; h += 256) {
    float xv = xr[h];
    accs += xv * sgw[h];
    #pragma unroll
    for (int e = 0; e < N_EXP; e++) acc[e] += xv * rw[e * H_DIM + h];
  }
  __shared__ float red[4][N_EXP];
  __shared__ float reds[4];
  __shared__ float logits[N_EXP];
  #pragma unroll
  for (int e = 0; e < N_EXP; e++) {
    float v = acc[e];
    for (int off = 32; off; off >>= 1) v += __shfl_down(v, off, 64);
    if (lane == 0) red[wave][e] = v;
  }
  {
    float v = accs;
    for (int off = 32; off; off >>= 1) v += __shfl_down(v, off, 64);
    if (lane == 0) reds[wave] = v;
  }
  __syncthreads();
  if (tid < N_EXP) logits[tid] = red[0][tid] + red[1][tid] + red[2][tid] + red[3][tid];
  __syncthreads();
  if (tid == 0) {
    float m = -1e30f;
    #pragma unroll
    for (int e = 0; e < N_EXP; e++) m = fmaxf(m, logits[e]);
    float p[N_EXP];
    #pragma unroll
    for (int e = 0; e < N_EXP; e++) p[e] = expf(logits[e] - m);
    int ids[TOPK]; float vs[TOPK]; float wsum = 0.f;
    #pragma unroll
    for (int k = 0; k < TOPK; k++) {
      int best = 0; float bv = -1.f;
      for (int e = 0; e < N_EXP; e++) {
        if (p[e] > bv) { bv = p[e]; best = e; }
      }
      ids[k] = best; vs[k] = bv; wsum += bv; p[best] = -2.f;
    }
    float inv = 1.f / wsum;
    float sgs = reds[0] + reds[1] + reds[2] + reds[3];
    sg[t] = 1.f / (1.f + expf(-sgs));
    #pragma unroll
    for (int k = 0; k < TOPK; k++) {
      int slot = t * TOPK + k;
      topw[slot] = vs[k] * inv;
      int pos = atomicAdd(&counts[ids[k]], 1);
      lists[ids[k] * T_TOK + pos] = slot;
    }
  }
}

// ------- fused gate/up dual GEMM + SwiGLU, 64x64 tile, BK=32, 512 threads -------
// 8 waves (2m x 4n), wave tile 32x16. Threads 0-255 stage Wg, 256-511 stage Wu.
// 2-deep register prefetch, swizzled LDS, one raw barrier per K-step.
// LDS 24KB -> 4 blocks/CU (wave-capped), 32 waves/CU.
__global__ __launch_bounds__(512, 8) void gateup_fused(
    const float* __restrict__ X,
    const float* __restrict__ wg_, const float* __restrict__ wu_,
    const float* __restrict__ swg, const float* __restrict__ swu,
    bf16* __restrict__ act, bf16* __restrict__ acts,
    const int* __restrict__ lists, const int* __restrict__ counts,
    int n_shared, int sh_nfb, int actsN, int col_off)
{
  int id = blockIdx.x;
  bool gather = id >= n_shared;
  const float *Wg, *Wu; const int* lb = nullptr;
  int count, mt, fb, ldb, Nout; bf16* C;
  if (gather) {
    int g = id - n_shared;
    int j = g >> 3;
    int e = (g & 7) + 8 * (j / 192);  // expert e's 192 blocks share an XCD
    int rr = j % 192;
    mt = (rr / 12) * 64; fb = (rr % 12) * 64;
    count = counts[e]; lb = lists + e * T_TOK;
    Wg = wg_ + (size_t)e * H_DIM * F_DIM;
    Wu = wu_ + (size_t)e * H_DIM * F_DIM;
    ldb = F_DIM; Nout = F_DIM; C = act;
  } else {
    fb = (id % sh_nfb) * 64; mt = (id / sh_nfb) * 64;
    count = T_TOK; ldb = FS_DIM; Nout = actsN;
    Wg = swg + col_off; Wu = swu + col_off;
    C = acts;
  }
  if (mt >= count) return;

  __shared__ alignas(16) char sA [2][64 * 64];   // [64m][32k] bf16, swizzled
  __shared__ alignas(16) char sBg[2][64 * 64];   // [64n][32k] bf16, swizzled
  __shared__ alignas(16) char sBu[2][64 * 64];

  int tid = threadIdx.x;
  int lane = tid & 63, wid = tid >> 6;
  int wr = wid >> 2, wc = wid & 3;   // 2m x 4n waves, wave tile 32m x 16n
  int l15 = lane & 15, qB = (lane >> 4) << 4;

  // A staging: row = tid>>3 (0..63), 16B fp32 at col (tid&7)*4
  const float* aptr;
  {
    int r = mt + (tid >> 3);
    int rc = r < count ? r : count - 1;
    int tok = gather ? (lb[rc] >> 2) : rc;
    aptr = X + (size_t)tok * H_DIM + ((tid & 7) << 2);
  }
  // B staging: thread half -> one matrix; each thread 2 k-rows x 4 n
  int t8 = tid & 255;
  int bng = t8 & 15;             // n-quad 0..15
  int bk2 = (t8 >> 4) << 1;      // k base 0,2,..,30
  const float* bptr = (tid < 256 ? Wg : Wu) + (size_t)bk2 * ldb + fb + bng * 4;
  char* bds = (tid < 256) ? &sBg[0][0] : &sBu[0][0];

  f32x4 accg[2], accu[2];
  #pragma unroll
  for (int m = 0; m < 2; m++) {
    accg[m] = (f32x4){0.f,0.f,0.f,0.f};
    accu[m] = (f32x4){0.f,0.f,0.f,0.f};
  }

  f32x4 ava, bva[2];    // prefetch set A
  f32x4 avb, bvb[2];    // prefetch set B

  #define GU_ISSUE(av, bv, k0) do {                                   \
    av = *(const f32x4*)(aptr + (k0));                                \
    bv[0] = *(const f32x4*)(bptr + (size_t)(k0) * ldb);               \
    bv[1] = *(const f32x4*)(bptr + (size_t)((k0) + 1) * ldb);         \
  } while (0)

  #define GU_STAGE(b, av, bv) do {                                    \
    bf16x4 ta;                                                        \
    ta[0]=(bf16)av[0]; ta[1]=(bf16)av[1];                             \
    ta[2]=(bf16)av[2]; ta[3]=(bf16)av[3];                             \
    *(bf16x4*)(sA[b] + swz(tid >> 3, (tid & 7) << 3)) = ta;           \
    _Pragma("unroll")                                                 \
    for (int i_ = 0; i_ < 4; i_++) {                                  \
      bf16x2 tb;                                                      \
      tb[0]=(bf16)bv[0][i_]; tb[1]=(bf16)bv[1][i_];                   \
      *(bf16x2*)(bds + (b) * (64 * 64) + swz(bng * 4 + i_, bk2 << 1)) = tb; \
    } } while (0)

  #define GU_MFMA(b) do {                                             \
    __builtin_amdgcn_s_setprio(1);                                    \
    bf16x8 af0 = *(const bf16x8*)(sA[b] + swz(wr * 32 + l15, qB));    \
    bf16x8 af1 = *(const bf16x8*)(sA[b] + swz(wr * 32 + 16 + l15, qB)); \
    int rb = wc * 16 + l15;                                           \
    bf16x8 bg = *(const bf16x8*)(sBg[b] + swz(rb, qB));               \
    bf16x8 bu = *(const bf16x8*)(sBu[b] + swz(rb, qB));               \
    accg[0] = __builtin_amdgcn_mfma_f32_16x16x32_bf16(af0, bg, accg[0], 0,0,0); \
    accg[1] = __builtin_amdgcn_mfma_f32_16x16x32_bf16(af1, bg, accg[1], 0,0,0); \
    accu[0] = __builtin_amdgcn_mfma_f32_16x16x32_bf16(af0, bu, accu[0], 0,0,0); \
    accu[1] = __builtin_amdgcn_mfma_f32_16x16x32_bf16(af1, bu, accu[1], 0,0,0); \
    __builtin_amdgcn_s_setprio(0);                                    \
  } while (0)

  const int NT = H_DIM / 32;   // 64
  GU_ISSUE(ava, bva, 0);
  GU_ISSUE(avb, bvb, 32);
  GU_STAGE(0, ava, bva);
  GU_ISSUE(ava, bva, 64);
  BAR();
  for (int t = 0; t < NT; t += 2) {
    GU_MFMA(0);                                    // tile t
    GU_STAGE(1, avb, bvb);                         // tile t+1
    if (t + 3 < NT) GU_ISSUE(avb, bvb, (t + 3) * 32);
    BAR();
    GU_MFMA(1);                                    // tile t+1
    if (t + 2 < NT) {
      GU_STAGE(0, ava, bva);                       // tile t+2
      if (t + 4 < NT) GU_ISSUE(ava, bva, (t + 4) * 32);
    }
    BAR();
  }
  #undef GU_ISSUE
  #undef GU_STAGE
  #undef GU_MFMA

  #pragma unroll
  for (int m = 0; m < 2; m++) {
    #pragma unroll
    for (int q = 0; q < 4; q++) {
      int gr = mt + wr * 32 + m * 16 + (lane >> 4) * 4 + q;
      if (gr < count) {
        size_t rowo = (gather ? (size_t)lb[gr] : (size_t)gr) * Nout;
        float g = accg[m][q], u = accu[m][q];
        C[rowo + fb + wc * 16 + l15] =
            (bf16)(g / (1.f + __expf(-g)) * u);
      }
    }
  }
}

// ------- fused down-proj, 64x128 tile, BK=32, 2-deep prefetch -------
// dedicated grid, XCD-clustered expert blocks (round 7/10/11 scheme, unchanged).
__global__ __launch_bounds__(256, 4) void down_fused(
    const bf16* __restrict__ act, const bf16* __restrict__ acts,
    const float* __restrict__ wd_, const float* __restrict__ swd,
    bf16* __restrict__ dslot, float* __restrict__ out,
    const float* __restrict__ sg,
    const int* __restrict__ lists, const int* __restrict__ counts,
    int n_shared, int lda_sh, int kd_sh, int swd_off, int accum)
{
  int id = blockIdx.x;
  bool expert = id >= n_shared;
  const bf16* A; const float* W; const int* lb = nullptr;
  int count, mt, nb, Kd, lda;
  if (expert) {
    int g = id - n_shared;
    int j = g >> 3;
    int e = (g & 7) + 8 * (j >> 7);   // expert e's 128 blocks share an XCD
    int rr = j & 127;
    nb = (rr & 15) * 128; mt = (rr >> 4) * 64;
    count = counts[e]; lb = lists + e * T_TOK;
    A = act; lda = F_DIM; Kd = F_DIM;
    W = wd_ + (size_t)e * F_DIM * H_DIM;
  } else {
    nb = (id & 15) * 128; mt = (id >> 4) * 64;
    count = T_TOK; A = acts; lda = lda_sh; Kd = kd_sh;
    W = swd + (size_t)swd_off * H_DIM;
  }
  if (mt >= count) return;

  __shared__ alignas(16) char sA[2][64 * 64];    // [64m][32k] bf16, swizzled
  __shared__ alignas(16) char sB[2][128 * 64];   // [128n][32k] bf16, swizzled

  int tid = threadIdx.x;
  int lane = tid & 63, wid = tid >> 6;
  int wr = wid >> 1, wc = wid & 1;   // wave tile: 32 rows x 64 cols
  int l15 = lane & 15, qB = (lane >> 4) << 4;
  int bng = tid & 31;
  int bk4 = (tid >> 5) << 2;

  const bf16* aptr;
  {
    int r = mt + (tid >> 2);
    int rc = r < count ? r : count - 1;
    int ar = expert ? lb[rc] : rc;
    aptr = A + (size_t)ar * lda + ((tid & 3) << 3);
  }
  const float* bptr = W + (size_t)bk4 * H_DIM + nb + bng * 4;

  f32x4 acc[2][4];
  #pragma unroll
  for (int m = 0; m < 2; m++)
    #pragma unroll
    for (int n = 0; n < 4; n++)
      acc[m][n] = (f32x4){0.f,0.f,0.f,0.f};

  uint4 ava, avb; f32x4 bva[4], bvb[4];

  #define DN_ISSUE(av, bv, k0) do {                                   \
    av = *(const uint4*)(aptr + (k0));                                \
    _Pragma("unroll")                                                 \
    for (int r_ = 0; r_ < 4; r_++)                                    \
      bv[r_] = *(const f32x4*)(bptr + (size_t)((k0) + r_) * H_DIM);   \
    } while (0)

  #define DN_STAGE(b, av, bv) do {                                    \
    *(uint4*)(sA[b] + swz(tid >> 2, (tid & 3) << 4)) = av;            \
    _Pragma("unroll")                                                 \
    for (int i_ = 0; i_ < 4; i_++) {                                  \
      bf16x4 tb;                                                      \
      tb[0]=(bf16)bv[0][i_]; tb[1]=(bf16)bv[1][i_];                   \
      tb[2]=(bf16)bv[2][i_]; tb[3]=(bf16)bv[3][i_];                   \
      *(bf16x4*)(sB[b] + swz(bng * 4 + i_, bk4 << 1)) = tb;           \
    } } while (0)

  #define DN_MFMA(b) do {                                             \
    __builtin_amdgcn_s_setprio(1);                                    \
    bf16x8 af0 = *(const bf16x8*)(sA[b] + swz(wr * 32 + l15, qB));    \
    bf16x8 af1 = *(const bf16x8*)(sA[b] + swz(wr * 32 + 16 + l15, qB)); \
    _Pragma("unroll")                                                 \
    for (int n_ = 0; n_ < 4; n_++) {                                  \
      bf16x8 bb = *(const bf16x8*)(sB[b] + swz(wc * 64 + n_ * 16 + l15, qB)); \
      acc[0][n_] = __builtin_amdgcn_mfma_f32_16x16x32_bf16(af0, bb, acc[0][n_], 0,0,0); \
      acc[1][n_] = __builtin_amdgcn_mfma_f32_16x16x32_bf16(af1, bb, acc[1][n_], 0,0,0); \
    }                                                                 \
    __builtin_amdgcn_s_setprio(0);                                    \
  } while (0)

  const int NT = Kd / 32;   // 24 or 64 (even)
  DN_ISSUE(ava, bva, 0);
  DN_ISSUE(avb, bvb, 32);
  DN_STAGE(0, ava, bva);
  DN_ISSUE(ava, bva, 64);
  BAR();
  for (int t = 0; t < NT; t += 2) {
    DN_MFMA(0);
    DN_STAGE(1, avb, bvb);
    if (t + 3 < NT) DN_ISSUE(avb, bvb, (t + 3) * 32);
    BAR();
    DN_MFMA(1);
    if (t + 2 < NT) {
      DN_STAGE(0, ava, bva);
      if (t + 4 < NT) DN_ISSUE(ava, bva, (t + 4) * 32);
    }
    BAR();
  }
  #undef DN_ISSUE
  #undef DN_STAGE
  #undef DN_MFMA

  #pragma unroll
  for (int m = 0; m < 2; m++) {
    #pragma unroll
    for (int q = 0; q < 4; q++) {
      int gr = mt + wr * 32 + m * 16 + (lane >> 4) * 4 + q;
      if (gr < count) {
        #pragma unroll
        for (int n = 0; n < 4; n++) {
          int col = nb + wc * 64 + n * 16 + l15;
          if (expert) {
            dslot[(size_t)lb[gr] * H_DIM + col] = (bf16)acc[m][n][q];
          } else if (!accum) {
            out[(size_t)gr * H_DIM + col] = sg[gr] * acc[m][n][q];
          } else {
            out[(size_t)gr * H_DIM + col] += sg[gr] * acc[m][n][q];
          }
        }
      }
    }
  }
}

// ---------------- combine: out += sum_k topw*dslot ----------------
__global__ __launch_bounds__(256) void combine_kernel(
    const bf16* __restrict__ dslot, const float* __restrict__ topw,
    float* __restrict__ out)
{
  int t = blockIdx.x;
  int h = threadIdx.x * 8;
  float w0 = topw[t * 4 + 0], w1 = topw[t * 4 + 1];
  float w2 = topw[t * 4 + 2], w3 = topw[t * 4 + 3];
  bf16x8 a0 = *(const bf16x8*)&dslot[(size_t)(t * 4 + 0) * H_DIM + h];
  bf16x8 a1 = *(const bf16x8*)&dslot[(size_t)(t * 4 + 1) * H_DIM + h];
  bf16x8 a2 = *(const bf16x8*)&dslot[(size_t)(t * 4 + 2) * H_DIM + h];
  bf16x8 a3 = *(const bf16x8*)&dslot[(size_t)(t * 4 + 3) * H_DIM + h];
  f32x4 o0 = *(f32x4*)&out[(size_t)t * H_DIM + h];
  f32x4 o1 = *(f32x4*)&out[(size_t)t * H_DIM + h + 4];
  float o[8] = {o0[0], o0[1], o0[2], o0[3], o1[0], o1[1], o1[2], o1[3]};
  #pragma unroll
  for (int j = 0; j < 8; j++)
    o[j] += w0 * (float)a0[j] + w1 * (float)a1[j] + w2 * (float)a2[j]
          + w3 * (float)a3[j];
  *(f32x4*)&out[(size_t)t * H_DIM + h]     = (f32x4){o[0], o[1], o[2], o[3]};
  *(f32x4*)&out[(size_t)t * H_DIM + h + 4] = (f32x4){o[4], o[5], o[6], o[7]};
}

extern "C" void kernel_launch(void* const* d_in, const int* in_sizes, int n_in,
                              void* d_out, int out_size, void* d_ws, size_t ws_size,
                              hipStream_t stream) {
  const float* x   = (const float*)d_in[0];
  const float* rw  = (const float*)d_in[1];
  const float* wg  = (const float*)d_in[2];
  const float* wu  = (const float*)d_in[3];
  const float* wd  = (const float*)d_in[4];
  const float* swg = (const float*)d_in[5];
  const float* swu = (const float*)d_in[6];
  const float* swd = (const float*)d_in[7];
  const float* sgw = (const float*)d_in[8];
  float* out = (float*)d_out;
  char* ws = (char*)d_ws;

  // full-FS path ~31.6 MB of ws; halves ~27.4 MB (34 MB overflowed in
  // round 3 -> replay divergence; gate at runtime)
  bool fullfs = ws_size >= (size_t)32000000;
  size_t actsN = fullfs ? FS_DIM : FS_HALF;
  int sh_nfb = (int)(actsN / 64);    // 64 or 32
  int nsh_gu = sh_nfb * (T_TOK / 64);

  size_t off = 0;
  int*   counts  = (int*)(ws + off); off += 256;
  int*   lists   = (int*)(ws + off); off += (size_t)N_EXP * T_TOK * 4;
  float* topw    = (float*)(ws + off); off += (size_t)T_TOK * TOPK * 4;
  float* sg      = (float*)(ws + off); off += (size_t)T_TOK * 4;
  bf16*  act     = (bf16*)(ws + off); off += (size_t)T_TOK * TOPK * F_DIM * 2;
  bf16*  acts    = (bf16*)(ws + off); off += (size_t)T_TOK * actsN * 2;
  bf16*  dslot   = (bf16*)(ws + off); off += (size_t)T_TOK * TOPK * H_DIM * 2;

  hipMemsetAsync(counts, 0, 256, stream);

  router_kernel<<<T_TOK, 256, 0, stream>>>(x, rw, sgw, topw, sg, counts, lists);

  const int EXP_GU = N_EXP * 192;   // 6144 (16 mt x 12 fb, early-exit)
  const int DN_EXP = N_EXP * 128;   // 4096

  if (fullfs) {
    gateup_fused<<<nsh_gu + EXP_GU, 512, 0, stream>>>(
        x, wg, wu, swg, swu, act, acts, lists, counts,
        nsh_gu, sh_nfb, FS_DIM, 0);
    down_fused<<<256 + DN_EXP, 256, 0, stream>>>(
        act, acts, wd, swd, dslot, out, sg, lists, counts,
        256, FS_DIM, FS_DIM, 0, 0);
  } else {
    gateup_fused<<<nsh_gu + EXP_GU, 512, 0, stream>>>(
        x, wg, wu, swg, swu, act, acts, lists, counts,
        nsh_gu, sh_nfb, FS_HALF, 0);
    down_fused<<<256 + DN_EXP, 256, 0, stream>>>(
        act, acts, wd, swd, dslot, out, sg, lists, counts,
        256, FS_HALF, FS_HALF, 0, 0);
    // second half of shared expert: grid = nsh_gu -> all blocks are shared
    gateup_fused<<<nsh_gu, 512, 0, stream>>>(
        x, wg, wu, swg, swu, act, acts, lists, counts,
        nsh_gu, sh_nfb, FS_HALF, FS_HALF);
    down_fused<<<256, 256, 0, stream>>>(
        act, acts, wd, swd, dslot, out, sg, lists, counts,
        256, FS_HALF, FS_HALF, FS_HALF, 1);
  }
  combine_kernel<<<T_TOK, 256, 0, stream>>>(dslot, topw, out);
}

// Round 13
// 374.043 us; speedup vs baseline: 2.3765x; 2.3765x over previous
//
#include <hip/hip_runtime.h>
#include <math.h>

#define T_TOK 1024
#define H_DIM 2048
#define N_EXP 32
#define TOPK  4
#define F_DIM 768
#define FS_DIM 4096
#define FS_HALF 2048

typedef __bf16 bf16;
typedef __attribute__((ext_vector_type(4))) __bf16 bf16x4;
typedef __attribute__((ext_vector_type(8))) __bf16 bf16x8;
typedef __attribute__((ext_vector_type(4))) float f32x4;

// raw barrier: drain ds ops (lgkm) but let global prefetch loads stay in
// flight across the barrier; sched_barrier(0) pins code motion at the BAR.
#define BAR() do {                                        \
    asm volatile("s_waitcnt lgkmcnt(0)" ::: "memory");    \
    __builtin_amdgcn_s_barrier();                         \
    __builtin_amdgcn_sched_barrier(0);                    \
  } while (0)

// XOR-swizzled LDS offset: rows are 32 bf16 = 64B.
__device__ __forceinline__ int swz(int row, int colB) {
  return row * 64 + (colB ^ (((row >> 2) & 3) << 4));
}

// ---------------- router: fp32 logits -> softmax -> top4 -> lists ----------------
__global__ __launch_bounds__(256) void router_kernel(
    const float* __restrict__ x, const float* __restrict__ rw,
    const float* __restrict__ sgw,
    float* __restrict__ topw, float* __restrict__ sg,
    int* __restrict__ counts, int* __restrict__ lists)
{
  int t = blockIdx.x; int tid = threadIdx.x;
  int lane = tid & 63, wave = tid >> 6;
  float acc[N_EXP];
  #pragma unroll
  for (int e = 0; e < N_EXP; e++) acc[e] = 0.f;
  float accs = 0.f;
  const float* xr = x + (size_t)t * H_DIM;
  for (int h = tid; h < H_DIM; h += 256) {
    float xv = xr[h];
    accs += xv * sgw[h];
    #pragma unroll
    for (int e = 0; e < N_EXP; e++) acc[e] += xv * rw[e * H_DIM + h];
  }
  __shared__ float red[4][N_EXP];
  __shared__ float reds[4];
  __shared__ float logits[N_EXP];
  #pragma unroll
  for (int e = 0; e < N_EXP; e++) {
    float v = acc[e];
    for (int off = 32; off; off >>= 1) v += __shfl_down(v, off, 64);
    if (lane == 0) red[wave][e] = v;
  }
  {
    float v = accs;
    for (int off = 32; off; off >>= 1) v += __shfl_down(v, off, 64);
    if (lane == 0) reds[wave] = v;
  }
  __syncthreads();
  if (tid < N_EXP) logits[tid] = red[0][tid] + red[1][tid] + red[2][tid] + red[3][tid];
  __syncthreads();
  if (tid == 0) {
    float m = -1e30f;
    #pragma unroll
    for (int e = 0; e < N_EXP; e++) m = fmaxf(m, logits[e]);
    float p[N_EXP];
    #pragma unroll
    for (int e = 0; e < N_EXP; e++) p[e] = expf(logits[e] - m);
    int ids[TOPK]; float vs[TOPK]; float wsum = 0.f;
    #pragma unroll
    for (int k = 0; k < TOPK; k++) {
      int best = 0; float bv = -1.f;
      for (int e = 0; e < N_EXP; e++) {
        if (p[e] > bv) { bv = p[e]; best = e; }
      }
      ids[k] = best; vs[k] = bv; wsum += bv; p[best] = -2.f;
    }
    float inv = 1.f / wsum;
    float sgs = reds[0] + reds[1] + reds[2] + reds[3];
    sg[t] = 1.f / (1.f + expf(-sgs));
    #pragma unroll
    for (int k = 0; k < TOPK; k++) {
      int slot = t * TOPK + k;
      topw[slot] = vs[k] * inv;
      int pos = atomicAdd(&counts[ids[k]], 1);
      lists[ids[k] * T_TOK + pos] = slot;
    }
  }
}

// ------- fused gate/up dual GEMM + SwiGLU, 64x128 tile, BK=32, 512 threads -------
// 8 waves (2x4), wave tile 32x32. Threads 0-255 stage Wg, 256-511 stage Wu.
// 2-deep register prefetch, swizzled LDS, one raw barrier per K-step.
// waves_per_eu(4,4): allocator budget 128 VGPR, no 8-wave targeting -> staging
// stays in registers (round 12's (512,8) cap caused catastrophic spill).
__global__ __launch_bounds__(512) __attribute__((amdgpu_waves_per_eu(4, 4)))
void gateup_fused(
    const float* __restrict__ X,
    const float* __restrict__ wg_, const float* __restrict__ wu_,
    const float* __restrict__ swg, const float* __restrict__ swu,
    bf16* __restrict__ act, bf16* __restrict__ acts,
    const int* __restrict__ lists, const int* __restrict__ counts,
    int n_shared, int sh_nfb, int actsN, int col_off)
{
  int id = blockIdx.x;
  bool gather = id >= n_shared;
  const float *Wg, *Wu; const int* lb = nullptr;
  int count, mt, fb, ldb, Nout; bf16* C;
  if (gather) {
    int g = id - n_shared;
    int j = g >> 3;
    int e = (g & 7) + 8 * (j / 96);   // expert e's 96 blocks share an XCD
    int rr = j % 96;
    mt = (rr / 6) * 64; fb = (rr % 6) * 128;
    count = counts[e]; lb = lists + e * T_TOK;
    Wg = wg_ + (size_t)e * H_DIM * F_DIM;
    Wu = wu_ + (size_t)e * H_DIM * F_DIM;
    ldb = F_DIM; Nout = F_DIM; C = act;
  } else {
    fb = (id % sh_nfb) * 128; mt = (id / sh_nfb) * 64;
    count = T_TOK; ldb = FS_DIM; Nout = actsN;
    Wg = swg + col_off; Wu = swu + col_off;
    C = acts;
  }
  if (mt >= count) return;

  __shared__ alignas(16) char sA [2][64 * 64];    // [64m][32k] bf16, swizzled
  __shared__ alignas(16) char sBg[2][128 * 64];   // [128n][32k] bf16, swizzled
  __shared__ alignas(16) char sBu[2][128 * 64];

  int tid = threadIdx.x;
  int lane = tid & 63, wid = tid >> 6;
  int wr = wid >> 2, wc = wid & 3;   // 2x4 waves, wave tile 32m x 32n
  int l15 = lane & 15, qB = (lane >> 4) << 4;

  // A staging: row = tid>>3 (0..63), 16B fp32 at col (tid&7)*4
  const float* aptr;
  {
    int r = mt + (tid >> 3);
    int rc = r < count ? r : count - 1;
    int tok = gather ? (lb[rc] >> 2) : rc;
    aptr = X + (size_t)tok * H_DIM + ((tid & 7) << 2);
  }
  // B staging: thread half -> one matrix; 4n x 4k block each
  int t8 = tid & 255;
  int bng = t8 & 31;             // n-quad 0..31
  int bk4 = (t8 >> 5) << 2;      // k base 0,4,..,28
  const float* bptr = (tid < 256 ? Wg : Wu) + (size_t)bk4 * ldb + fb + bng * 4;
  char* bds = (tid < 256) ? &sBg[0][0] : &sBu[0][0];

  f32x4 accg[2][2], accu[2][2];
  #pragma unroll
  for (int m = 0; m < 2; m++)
    #pragma unroll
    for (int n = 0; n < 2; n++) {
      accg[m][n] = (f32x4){0.f,0.f,0.f,0.f};
      accu[m][n] = (f32x4){0.f,0.f,0.f,0.f};
    }

  f32x4 ava, bva[4];    // prefetch set A
  f32x4 avb, bvb[4];    // prefetch set B

  // sched_barrier(0) after the loads pins them at the issue point (the
  // compiler may not sink them toward their use).
  #define GU_ISSUE(av, bv, k0) do {                                   \
    av = *(const f32x4*)(aptr + (k0));                                \
    _Pragma("unroll")                                                 \
    for (int r_ = 0; r_ < 4; r_++)                                    \
      bv[r_] = *(const f32x4*)(bptr + (size_t)((k0) + r_) * ldb);     \
    __builtin_amdgcn_sched_barrier(0);                                \
  } while (0)

  #define GU_STAGE(b, av, bv) do {                                    \
    bf16x4 ta;                                                        \
    ta[0]=(bf16)av[0]; ta[1]=(bf16)av[1];                             \
    ta[2]=(bf16)av[2]; ta[3]=(bf16)av[3];                             \
    *(bf16x4*)(sA[b] + swz(tid >> 3, (tid & 7) << 3)) = ta;           \
    _Pragma("unroll")                                                 \
    for (int i_ = 0; i_ < 4; i_++) {                                  \
      bf16x4 tb;                                                      \
      tb[0]=(bf16)bv[0][i_]; tb[1]=(bf16)bv[1][i_];                   \
      tb[2]=(bf16)bv[2][i_]; tb[3]=(bf16)bv[3][i_];                   \
      *(bf16x4*)(bds + (b) * (128 * 64) + swz(bng * 4 + i_, bk4 << 1)) = tb; \
    } } while (0)

  #define GU_MFMA(b) do {                                             \
    __builtin_amdgcn_s_setprio(1);                                    \
    bf16x8 af0 = *(const bf16x8*)(sA[b] + swz(wr * 32 + l15, qB));    \
    bf16x8 af1 = *(const bf16x8*)(sA[b] + swz(wr * 32 + 16 + l15, qB)); \
    _Pragma("unroll")                                                 \
    for (int n_ = 0; n_ < 2; n_++) {                                  \
      int rb = wc * 32 + n_ * 16 + l15;                               \
      bf16x8 bg = *(const bf16x8*)(sBg[b] + swz(rb, qB));             \
      bf16x8 bu = *(const bf16x8*)(sBu[b] + swz(rb, qB));             \
      accg[0][n_] = __builtin_amdgcn_mfma_f32_16x16x32_bf16(af0, bg, accg[0][n_], 0,0,0); \
      accg[1][n_] = __builtin_amdgcn_mfma_f32_16x16x32_bf16(af1, bg, accg[1][n_], 0,0,0); \
      accu[0][n_] = __builtin_amdgcn_mfma_f32_16x16x32_bf16(af0, bu, accu[0][n_], 0,0,0); \
      accu[1][n_] = __builtin_amdgcn_mfma_f32_16x16x32_bf16(af1, bu, accu[1][n_], 0,0,0); \
    }                                                                 \
    __builtin_amdgcn_s_setprio(0);                                    \
  } while (0)

  const int NT = H_DIM / 32;   // 64
  GU_ISSUE(ava, bva, 0);
  GU_ISSUE(avb, bvb, 32);
  GU_STAGE(0, ava, bva);
  GU_ISSUE(ava, bva, 64);
  BAR();
  for (int t = 0; t < NT; t += 2) {
    GU_MFMA(0);                                    // tile t
    GU_STAGE(1, avb, bvb);                         // tile t+1
    if (t + 3 < NT) GU_ISSUE(avb, bvb, (t + 3) * 32);
    BAR();
    GU_MFMA(1);                                    // tile t+1
    if (t + 2 < NT) {
      GU_STAGE(0, ava, bva);                       // tile t+2
      if (t + 4 < NT) GU_ISSUE(ava, bva, (t + 4) * 32);
    }
    BAR();
  }
  #undef GU_ISSUE
  #undef GU_STAGE
  #undef GU_MFMA

  #pragma unroll
  for (int m = 0; m < 2; m++) {
    #pragma unroll
    for (int q = 0; q < 4; q++) {
      int gr = mt + wr * 32 + m * 16 + (lane >> 4) * 4 + q;
      if (gr < count) {
        size_t rowo = (gather ? (size_t)lb[gr] : (size_t)gr) * Nout;
        #pragma unroll
        for (int n = 0; n < 2; n++) {
          float g = accg[m][n][q], u = accu[m][n][q];
          C[rowo + fb + wc * 32 + n * 16 + l15] =
              (bf16)(g / (1.f + __expf(-g)) * u);
        }
      }
    }
  }
}

// ------- fused down-proj, 64x128 tile, BK=32, 2-deep prefetch -------
// dedicated grid, XCD-clustered expert blocks (round 7/10/11 scheme, unchanged).
__global__ __launch_bounds__(256, 4) void down_fused(
    const bf16* __restrict__ act, const bf16* __restrict__ acts,
    const float* __restrict__ wd_, const float* __restrict__ swd,
    bf16* __restrict__ dslot, float* __restrict__ out,
    const float* __restrict__ sg,
    const int* __restrict__ lists, const int* __restrict__ counts,
    int n_shared, int lda_sh, int kd_sh, int swd_off, int accum)
{
  int id = blockIdx.x;
  bool expert = id >= n_shared;
  const bf16* A; const float* W; const int* lb = nullptr;
  int count, mt, nb, Kd, lda;
  if (expert) {
    int g = id - n_shared;
    int j = g >> 3;
    int e = (g & 7) + 8 * (j >> 7);   // expert e's 128 blocks share an XCD
    int rr = j & 127;
    nb = (rr & 15) * 128; mt = (rr >> 4) * 64;
    count = counts[e]; lb = lists + e * T_TOK;
    A = act; lda = F_DIM; Kd = F_DIM;
    W = wd_ + (size_t)e * F_DIM * H_DIM;
  } else {
    nb = (id & 15) * 128; mt = (id >> 4) * 64;
    count = T_TOK; A = acts; lda = lda_sh; Kd = kd_sh;
    W = swd + (size_t)swd_off * H_DIM;
  }
  if (mt >= count) return;

  __shared__ alignas(16) char sA[2][64 * 64];    // [64m][32k] bf16, swizzled
  __shared__ alignas(16) char sB[2][128 * 64];   // [128n][32k] bf16, swizzled

  int tid = threadIdx.x;
  int lane = tid & 63, wid = tid >> 6;
  int wr = wid >> 1, wc = wid & 1;   // wave tile: 32 rows x 64 cols
  int l15 = lane & 15, qB = (lane >> 4) << 4;
  int bng = tid & 31;
  int bk4 = (tid >> 5) << 2;

  const bf16* aptr;
  {
    int r = mt + (tid >> 2);
    int rc = r < count ? r : count - 1;
    int ar = expert ? lb[rc] : rc;
    aptr = A + (size_t)ar * lda + ((tid & 3) << 3);
  }
  const float* bptr = W + (size_t)bk4 * H_DIM + nb + bng * 4;

  f32x4 acc[2][4];
  #pragma unroll
  for (int m = 0; m < 2; m++)
    #pragma unroll
    for (int n = 0; n < 4; n++)
      acc[m][n] = (f32x4){0.f,0.f,0.f,0.f};

  uint4 ava, avb; f32x4 bva[4], bvb[4];

  #define DN_ISSUE(av, bv, k0) do {                                   \
    av = *(const uint4*)(aptr + (k0));                                \
    _Pragma("unroll")                                                 \
    for (int r_ = 0; r_ < 4; r_++)                                    \
      bv[r_] = *(const f32x4*)(bptr + (size_t)((k0) + r_) * H_DIM);   \
    } while (0)

  #define DN_STAGE(b, av, bv) do {                                    \
    *(uint4*)(sA[b] + swz(tid >> 2, (tid & 3) << 4)) = av;            \
    _Pragma("unroll")                                                 \
    for (int i_ = 0; i_ < 4; i_++) {                                  \
      bf16x4 tb;                                                      \
      tb[0]=(bf16)bv[0][i_]; tb[1]=(bf16)bv[1][i_];                   \
      tb[2]=(bf16)bv[2][i_]; tb[3]=(bf16)bv[3][i_];                   \
      *(bf16x4*)(sB[b] + swz(bng * 4 + i_, bk4 << 1)) = tb;           \
    } } while (0)

  #define DN_MFMA(b) do {                                             \
    __builtin_amdgcn_s_setprio(1);                                    \
    bf16x8 af0 = *(const bf16x8*)(sA[b] + swz(wr * 32 + l15, qB));    \
    bf16x8 af1 = *(const bf16x8*)(sA[b] + swz(wr * 32 + 16 + l15, qB)); \
    _Pragma("unroll")                                                 \
    for (int n_ = 0; n_ < 4; n_++) {                                  \
      bf16x8 bb = *(const bf16x8*)(sB[b] + swz(wc * 64 + n_ * 16 + l15, qB)); \
      acc[0][n_] = __builtin_amdgcn_mfma_f32_16x16x32_bf16(af0, bb, acc[0][n_], 0,0,0); \
      acc[1][n_] = __builtin_amdgcn_mfma_f32_16x16x32_bf16(af1, bb, acc[1][n_], 0,0,0); \
    }                                                                 \
    __builtin_amdgcn_s_setprio(0);                                    \
  } while (0)

  const int NT = Kd / 32;   // 24 or 64 (even)
  DN_ISSUE(ava, bva, 0);
  DN_ISSUE(avb, bvb, 32);
  DN_STAGE(0, ava, bva);
  DN_ISSUE(ava, bva, 64);
  BAR();
  for (int t = 0; t < NT; t += 2) {
    DN_MFMA(0);
    DN_STAGE(1, avb, bvb);
    if (t + 3 < NT) DN_ISSUE(avb, bvb, (t + 3) * 32);
    BAR();
    DN_MFMA(1);
    if (t + 2 < NT) {
      DN_STAGE(0, ava, bva);
      if (t + 4 < NT) DN_ISSUE(ava, bva, (t + 4) * 32);
    }
    BAR();
  }
  #undef DN_ISSUE
  #undef DN_STAGE
  #undef DN_MFMA

  #pragma unroll
  for (int m = 0; m < 2; m++) {
    #pragma unroll
    for (int q = 0; q < 4; q++) {
      int gr = mt + wr * 32 + m * 16 + (lane >> 4) * 4 + q;
      if (gr < count) {
        #pragma unroll
        for (int n = 0; n < 4; n++) {
          int col = nb + wc * 64 + n * 16 + l15;
          if (expert) {
            dslot[(size_t)lb[gr] * H_DIM + col] = (bf16)acc[m][n][q];
          } else if (!accum) {
            out[(size_t)gr * H_DIM + col] = sg[gr] * acc[m][n][q];
          } else {
            out[(size_t)gr * H_DIM + col] += sg[gr] * acc[m][n][q];
          }
        }
      }
    }
  }
}

// ---------------- combine: out += sum_k topw*dslot ----------------
__global__ __launch_bounds__(256) void combine_kernel(
    const bf16* __restrict__ dslot, const float* __restrict__ topw,
    float* __restrict__ out)
{
  int t = blockIdx.x;
  int h = threadIdx.x * 8;
  float w0 = topw[t * 4 + 0], w1 = topw[t * 4 + 1];
  float w2 = topw[t * 4 + 2], w3 = topw[t * 4 + 3];
  bf16x8 a0 = *(const bf16x8*)&dslot[(size_t)(t * 4 + 0) * H_DIM + h];
  bf16x8 a1 = *(const bf16x8*)&dslot[(size_t)(t * 4 + 1) * H_DIM + h];
  bf16x8 a2 = *(const bf16x8*)&dslot[(size_t)(t * 4 + 2) * H_DIM + h];
  bf16x8 a3 = *(const bf16x8*)&dslot[(size_t)(t * 4 + 3) * H_DIM + h];
  f32x4 o0 = *(f32x4*)&out[(size_t)t * H_DIM + h];
  f32x4 o1 = *(f32x4*)&out[(size_t)t * H_DIM + h + 4];
  float o[8] = {o0[0], o0[1], o0[2], o0[3], o1[0], o1[1], o1[2], o1[3]};
  #pragma unroll
  for (int j = 0; j < 8; j++)
    o[j] += w0 * (float)a0[j] + w1 * (float)a1[j] + w2 * (float)a2[j]
          + w3 * (float)a3[j];
  *(f32x4*)&out[(size_t)t * H_DIM + h]     = (f32x4){o[0], o[1], o[2], o[3]};
  *(f32x4*)&out[(size_t)t * H_DIM + h + 4] = (f32x4){o[4], o[5], o[6], o[7]};
}

extern "C" void kernel_launch(void* const* d_in, const int* in_sizes, int n_in,
                              void* d_out, int out_size, void* d_ws, size_t ws_size,
                              hipStream_t stream) {
  const float* x   = (const float*)d_in[0];
  const float* rw  = (const float*)d_in[1];
  const float* wg  = (const float*)d_in[2];
  const float* wu  = (const float*)d_in[3];
  const float* wd  = (const float*)d_in[4];
  const float* swg = (const float*)d_in[5];
  const float* swu = (const float*)d_in[6];
  const float* swd = (const float*)d_in[7];
  const float* sgw = (const float*)d_in[8];
  float* out = (float*)d_out;
  char* ws = (char*)d_ws;

  // full-FS path ~31.6 MB of ws; halves ~27.4 MB (34 MB overflowed in
  // round 3 -> replay divergence; gate at runtime)
  bool fullfs = ws_size >= (size_t)32000000;
  size_t actsN = fullfs ? FS_DIM : FS_HALF;
  int sh_nfb = (int)(actsN / 128);   // 32 or 16
  int nsh_gu = sh_nfb * (T_TOK / 64);

  size_t off = 0;
  int*   counts  = (int*)(ws + off); off += 256;
  int*   lists   = (int*)(ws + off); off += (size_t)N_EXP * T_TOK * 4;
  float* topw    = (float*)(ws + off); off += (size_t)T_TOK * TOPK * 4;
  float* sg      = (float*)(ws + off); off += (size_t)T_TOK * 4;
  bf16*  act     = (bf16*)(ws + off); off += (size_t)T_TOK * TOPK * F_DIM * 2;
  bf16*  acts    = (bf16*)(ws + off); off += (size_t)T_TOK * actsN * 2;
  bf16*  dslot   = (bf16*)(ws + off); off += (size_t)T_TOK * TOPK * H_DIM * 2;

  hipMemsetAsync(counts, 0, 256, stream);

  router_kernel<<<T_TOK, 256, 0, stream>>>(x, rw, sgw, topw, sg, counts, lists);

  const int EXP_GU = N_EXP * 96;    // 3072 (full mt coverage, early-exit)
  const int DN_EXP = N_EXP * 128;   // 4096

  if (fullfs) {
    gateup_fused<<<nsh_gu + EXP_GU, 512, 0, stream>>>(
        x, wg, wu, swg, swu, act, acts, lists, counts,
        nsh_gu, sh_nfb, FS_DIM, 0);
    down_fused<<<256 + DN_EXP, 256, 0, stream>>>(
        act, acts, wd, swd, dslot, out, sg, lists, counts,
        256, FS_DIM, FS_DIM, 0, 0);
  } else {
    gateup_fused<<<nsh_gu + EXP_GU, 512, 0, stream>>>(
        x, wg, wu, swg, swu, act, acts, lists, counts,
        nsh_gu, sh_nfb, FS_HALF, 0);
    down_fused<<<256 + DN_EXP, 256, 0, stream>>>(
        act, acts, wd, swd, dslot, out, sg, lists, counts,
        256, FS_HALF, FS_HALF, 0, 0);
    // second half of shared expert: grid = nsh_gu -> all blocks are shared
    gateup_fused<<<nsh_gu, 512, 0, stream>>>(
        x, wg, wu, swg, swu, act, acts, lists, counts,
        nsh_gu, sh_nfb, FS_HALF, FS_HALF);
    down_fused<<<256, 256, 0, stream>>>(
        act, acts, wd, swd, dslot, out, sg, lists, counts,
        256, FS_HALF, FS_HALF, FS_HALF, 1);
  }
  combine_kernel<<<T_TOK, 256, 0, stream>>>(dslot, topw, out);
}